// Round 6
// baseline (983.906 us; speedup 1.0000x reference)
//
#include <hip/hip_runtime.h>

#define NN 100000
#define NE 800000
#define DD 16
#define ALPHA 0.1f
#define NB0 391   // (NN+255)/256

__device__ __forceinline__ void load16(const float* __restrict__ p, float* r) {
  float4 v0 = *(const float4*)(p + 0);
  float4 v1 = *(const float4*)(p + 4);
  float4 v2 = *(const float4*)(p + 8);
  float4 v3 = *(const float4*)(p + 12);
  r[0]=v0.x; r[1]=v0.y; r[2]=v0.z; r[3]=v0.w;
  r[4]=v1.x; r[5]=v1.y; r[6]=v1.z; r[7]=v1.w;
  r[8]=v2.x; r[9]=v2.y; r[10]=v2.z; r[11]=v2.w;
  r[12]=v3.x; r[13]=v3.y; r[14]=v3.z; r[15]=v3.w;
}

__device__ __forceinline__ void store16(float* __restrict__ p, const float* r) {
  *(float4*)(p + 0)  = make_float4(r[0], r[1], r[2], r[3]);
  *(float4*)(p + 4)  = make_float4(r[4], r[5], r[6], r[7]);
  *(float4*)(p + 8)  = make_float4(r[8], r[9], r[10], r[11]);
  *(float4*)(p + 12) = make_float4(r[12], r[13], r[14], r[15]);
}

__device__ __forceinline__ unsigned f2bf(float x) {  // RNE f32 -> bf16 bits
  unsigned b = __float_as_uint(x);
  return (b + 0x7FFFu + ((b >> 16) & 1u)) >> 16;
}

// ---------------------------------------------------------------------------
// hist + rank over unified [in | out] histogram of length 2N (ranks: ushort)
// ---------------------------------------------------------------------------
__global__ __launch_bounds__(256) void hist_kernel(
    const int* __restrict__ ei, int* __restrict__ hist,
    unsigned short* __restrict__ rank_dst, unsigned short* __restrict__ rank_src)
{
  int e = blockIdx.x * 256 + threadIdx.x;
  if (e >= NE) return;
  int s = ei[e];
  int d = ei[NE + e];
  rank_dst[e] = (unsigned short)atomicAdd(&hist[d], 1);
  rank_src[e] = (unsigned short)atomicAdd(&hist[NN + s], 1);
}

__global__ __launch_bounds__(256) void scan1_kernel(
    const int* __restrict__ in, int* __restrict__ out, int* __restrict__ sums, int L)
{
  __shared__ int sh[256];
  int t = threadIdx.x;
  int i0 = blockIdx.x * 1024 + t * 4;
  int v0 = (i0 + 0 < L) ? in[i0 + 0] : 0;
  int v1 = (i0 + 1 < L) ? in[i0 + 1] : 0;
  int v2 = (i0 + 2 < L) ? in[i0 + 2] : 0;
  int v3 = (i0 + 3 < L) ? in[i0 + 3] : 0;
  int tot = v0 + v1 + v2 + v3;
  sh[t] = tot;
  __syncthreads();
  int val = tot;
  for (int off = 1; off < 256; off <<= 1) {
    int x = (t >= off) ? sh[t - off] : 0;
    __syncthreads();
    val += x; sh[t] = val;
    __syncthreads();
  }
  if (t == 255) sums[blockIdx.x] = val;
  int run = val - tot;
  if (i0 + 0 < L) out[i0 + 0] = run; run += v0;
  if (i0 + 1 < L) out[i0 + 1] = run; run += v1;
  if (i0 + 2 < L) out[i0 + 2] = run; run += v2;
  if (i0 + 3 < L) out[i0 + 3] = run;
}

__global__ __launch_bounds__(256) void scan2_kernel(
    int* __restrict__ sums, int nb, int* __restrict__ out_total)
{
  __shared__ int sh[256];
  int t = threadIdx.x;
  int v = (t < nb) ? sums[t] : 0;
  sh[t] = v;
  __syncthreads();
  int val = v;
  for (int off = 1; off < 256; off <<= 1) {
    int x = (t >= off) ? sh[t - off] : 0;
    __syncthreads();
    val += x; sh[t] = val;
    __syncthreads();
  }
  if (t < nb) sums[t] = val - v;
  if (t == 255) *out_total = val;   // sentinel = 2*NE at base[2N]
}

__global__ __launch_bounds__(256) void scan3_kernel(
    int* __restrict__ out, const int* __restrict__ sums, int L)
{
  int i = blockIdx.x * 256 + threadIdx.x;
  if (i < L) out[i] += sums[i >> 10];
}

// atomic-free scatter. pay.x packs {nbr:17 | sl:1<<17 | g_local:8<<18}
__global__ __launch_bounds__(256) void scatter_kernel(
    const int* __restrict__ ei, const float* __restrict__ ea, const float* __restrict__ a,
    const int* __restrict__ base,
    const unsigned short* __restrict__ rank_dst, const unsigned short* __restrict__ rank_src,
    uint4* __restrict__ pay, float2* __restrict__ pay_au)
{
  int e = blockIdx.x * 256 + threadIdx.x;
  if (e >= NE) return;
  int s = ei[e];
  int d = ei[NE + e];
  unsigned u0 = __float_as_uint(ea[3 * (size_t)e]);
  unsigned u1 = __float_as_uint(ea[3 * (size_t)e + 1]);
  unsigned u2 = __float_as_uint(ea[3 * (size_t)e + 2]);
  unsigned slbit = (s == d) ? (1u << 17) : 0u;

  int pd = base[d] + rank_dst[e];
  unsigned pxd = (slbit ? slbit : (unsigned)s) | ((unsigned)(d & 255) << 18);
  pay[pd] = make_uint4(pxd, u0, u1, u2);

  int ps = base[NN + s] + rank_src[e];
  unsigned pxs = (slbit ? slbit : (unsigned)d) | ((unsigned)(s & 255) << 18);
  pay[ps] = make_uint4(pxs, u0, u1, u2);
  pay_au[ps - NE] = make_float2(__int_as_float(d), a[e]);
}

// ---------------------------------------------------------------------------
// Edge-parallel gather. Block b < 2*NB0 owns 256 consecutive (node,dir)
// groups; their edges are one contiguous pay range (CSR). Phase 1: p1 per
// group in LDS. Phase 2: one lane per edge, accumulate relu(hid) via LDS
// atomics. Phase 3: per-group layer 2 + store.
// Blocks >= gblocks (WITH_AU): au_loss for previous iteration's u.
// ---------------------------------------------------------------------------
template<bool FIRST, bool WITH_AU>
__global__ __launch_bounds__(256) void gather_kernel(
    const float* __restrict__ h, const unsigned short* __restrict__ hb,
    const uint4* __restrict__ pay, const int* __restrict__ base,
    const float* __restrict__ to_w1, const float* __restrict__ to_b1,
    const float* __restrict__ to_w2, const float* __restrict__ to_b2,
    const float* __restrict__ fr_w1, const float* __restrict__ fr_b1,
    const float* __restrict__ fr_w2, const float* __restrict__ fr_b2,
    float* __restrict__ mto, float* __restrict__ mfr, int gblocks,
    const float2* __restrict__ pay_au, const float* __restrict__ u,
    const float* __restrict__ y, float w, float* __restrict__ loss)
{
  __shared__ float sw[848];          // w1[560] | b1 @560 | w2 @576 | b2 @832
  __shared__ float p1s[256 * 17];    // per-group own-projection (stride 17)
  __shared__ float accs[256 * 17];   // per-group sum(relu) [0..15] + cnt [16]
  __shared__ float ss[4];

  int t = threadIdx.x;

  if (WITH_AU && (int)blockIdx.x >= gblocks) {
    // ---- au_loss body ----
    int n = (blockIdx.x - gblocks) * 256 + t;
    float acc = 0.0f;
    if (n < NN) {
      float au = 0.0f;
      int beg = base[NN + n] - NE, end = base[NN + n + 1] - NE;
      for (int i = beg; i < end; ++i) {
        float2 q = pay_au[i];
        au = fmaf(q.y, u[__float_as_int(q.x)], au);
      }
      float dlt = au - y[n];
      acc = dlt * dlt;
    }
    #pragma unroll
    for (int off = 32; off > 0; off >>= 1) acc += __shfl_down(acc, off);
    int lane = t & 63, wid = t >> 6;
    if (lane == 0) ss[wid] = acc;
    __syncthreads();
    if (t == 0) atomicAdd(loss, (ss[0] + ss[1] + ss[2] + ss[3]) * w);
    return;
  }

  // ---- gather body ----
  int b = blockIdx.x;
  int dir = (b >= NB0) ? 1 : 0;
  int n0 = (dir ? (b - NB0) : b) * 256;
  int n1 = min(n0 + 256, NN);
  int gid0 = dir * NN + n0;
  int ebeg = base[gid0];
  int eend = base[dir * NN + n1];

  // stage weights for this block's direction
  {
    const float* w1p = dir ? fr_w1 : to_w1;
    const float* w2p = dir ? fr_w2 : to_w2;
    const float* b1p = dir ? fr_b1 : to_b1;
    const float* b2p = dir ? fr_b2 : to_b2;
    for (int i = t; i < 560; i += 256) sw[i] = w1p[i];
    if (t < 256) sw[576 + t] = w2p[t];
    if (t < 16) { sw[560 + t] = b1p[t]; sw[832 + t] = b2p[t]; }
  }
  for (int i = t; i < 256 * 17; i += 256) accs[i] = 0.0f;
  __syncthreads();

  // phase 1: p1[g] = b1 + h[own] @ W1[0:16]  (once per group)
  if (t < n1 - n0) {
    float pv[DD];
    #pragma unroll
    for (int j = 0; j < DD; ++j) pv[j] = sw[560 + j];
    if (!FIRST) {
      float hv[DD];
      load16(h + (size_t)(n0 + t) * DD, hv);
      #pragma unroll
      for (int k = 0; k < DD; ++k) {
        float x = hv[k];
        #pragma unroll
        for (int j = 0; j < DD; ++j) pv[j] = fmaf(x, sw[k * DD + j], pv[j]);
      }
    }
    #pragma unroll
    for (int j = 0; j < DD; ++j) p1s[t * 17 + j] = pv[j];
  }
  __syncthreads();

  // phase 2: one lane per edge
  for (int i = ebeg + t; i < eend; i += 256) {
    uint4 q = pay[i];
    unsigned px = q.x;
    if (px & (1u << 17)) continue;          // self-loop: contributes nothing
    int gl = px >> 18;
    float a0 = __uint_as_float(q.y), a1 = __uint_as_float(q.z), a2 = __uint_as_float(q.w);

    float hid[DD];
    #pragma unroll
    for (int j = 0; j < DD; ++j)
      hid[j] = fmaf(a0, sw[512 + j],
               fmaf(a1, sw[528 + j],
               fmaf(a2, sw[544 + j], p1s[gl * 17 + j])));

    if (!FIRST) {
      int nbr = px & 0x1FFFF;
      uint4 qa = *(const uint4*)(hb + (size_t)nbr * DD);
      uint4 qb = *(const uint4*)(hb + (size_t)nbr * DD + 8);
      float hv[DD];
      hv[0]  = __uint_as_float(qa.x << 16); hv[1]  = __uint_as_float(qa.x & 0xFFFF0000u);
      hv[2]  = __uint_as_float(qa.y << 16); hv[3]  = __uint_as_float(qa.y & 0xFFFF0000u);
      hv[4]  = __uint_as_float(qa.z << 16); hv[5]  = __uint_as_float(qa.z & 0xFFFF0000u);
      hv[6]  = __uint_as_float(qa.w << 16); hv[7]  = __uint_as_float(qa.w & 0xFFFF0000u);
      hv[8]  = __uint_as_float(qb.x << 16); hv[9]  = __uint_as_float(qb.x & 0xFFFF0000u);
      hv[10] = __uint_as_float(qb.y << 16); hv[11] = __uint_as_float(qb.y & 0xFFFF0000u);
      hv[12] = __uint_as_float(qb.z << 16); hv[13] = __uint_as_float(qb.z & 0xFFFF0000u);
      hv[14] = __uint_as_float(qb.w << 16); hv[15] = __uint_as_float(qb.w & 0xFFFF0000u);
      #pragma unroll
      for (int k = 0; k < DD; ++k) {
        float x = hv[k];
        #pragma unroll
        for (int j = 0; j < DD; ++j) hid[j] = fmaf(x, sw[(DD + k) * DD + j], hid[j]);
      }
    }

    #pragma unroll
    for (int j = 0; j < DD; ++j) atomicAdd(&accs[gl * 17 + j], fmaxf(hid[j], 0.0f));
    atomicAdd(&accs[gl * 17 + 16], 1.0f);
  }
  __syncthreads();

  // phase 3: layer 2 per group + store
  if (t < n1 - n0) {
    float c = accs[t * 17 + 16];
    float ms[DD];
    #pragma unroll
    for (int j = 0; j < DD; ++j) ms[j] = c * sw[832 + j];
    #pragma unroll
    for (int k = 0; k < DD; ++k) {
      float x = accs[t * 17 + k];
      #pragma unroll
      for (int j = 0; j < DD; ++j) ms[j] = fmaf(x, sw[576 + k * DD + j], ms[j]);
    }
    store16((dir ? mfr : mto) + (size_t)(n0 + t) * DD, ms);
  }
}

// ---------------------------------------------------------------------------
// Node kernel: h += ALPHA * psi([h, mto, mfr, prb]); u = dec(h); hb = bf16(h)
// ---------------------------------------------------------------------------
__global__ __launch_bounds__(256) void node_kernel(
    float* __restrict__ h, unsigned short* __restrict__ hb,
    const float* __restrict__ mto, const float* __restrict__ mfr,
    const float* __restrict__ prb,
    const float* __restrict__ psi_w1, const float* __restrict__ psi_b1,
    const float* __restrict__ psi_w2, const float* __restrict__ psi_b2,
    const float* __restrict__ dec_w1, const float* __restrict__ dec_b1,
    const float* __restrict__ dec_w2, const float* __restrict__ dec_b2,
    float* __restrict__ u)
{
  __shared__ float sw[1361];
  for (int i = threadIdx.x; i < 784; i += 256) sw[i] = psi_w1[i];
  { int i = threadIdx.x;
    if (i < 256) { sw[800 + i] = psi_w2[i]; sw[1072 + i] = dec_w1[i]; }
    if (i < 16) {
      sw[784 + i] = psi_b1[i];
      sw[1056 + i] = psi_b2[i];
      sw[1328 + i] = dec_b1[i];
      sw[1344 + i] = dec_w2[i];
    }
    if (i == 0) sw[1360] = dec_b2[0];
  }
  __syncthreads();

  int n = blockIdx.x * 256 + threadIdx.x;
  if (n >= NN) return;

  float hv[DD], mt[DD], mf[DD];
  load16(h + (size_t)n * DD, hv);
  load16(mto + (size_t)n * DD, mt);
  load16(mfr + (size_t)n * DD, mf);
  float p = prb[n];

  float hid[DD];
  #pragma unroll
  for (int j = 0; j < DD; ++j) hid[j] = sw[784 + j];
  #pragma unroll
  for (int i = 0; i < DD; ++i) {
    float x = hv[i];
    #pragma unroll
    for (int j = 0; j < DD; ++j) hid[j] = fmaf(x, sw[i * DD + j], hid[j]);
  }
  #pragma unroll
  for (int i = 0; i < DD; ++i) {
    float x = mt[i];
    #pragma unroll
    for (int j = 0; j < DD; ++j) hid[j] = fmaf(x, sw[(DD + i) * DD + j], hid[j]);
  }
  #pragma unroll
  for (int i = 0; i < DD; ++i) {
    float x = mf[i];
    #pragma unroll
    for (int j = 0; j < DD; ++j) hid[j] = fmaf(x, sw[(2 * DD + i) * DD + j], hid[j]);
  }
  #pragma unroll
  for (int j = 0; j < DD; ++j) hid[j] = fmaf(p, sw[48 * DD + j], hid[j]);
  #pragma unroll
  for (int j = 0; j < DD; ++j) hid[j] = fmaxf(hid[j], 0.0f);

  float hnew[DD];
  #pragma unroll
  for (int j = 0; j < DD; ++j) hnew[j] = sw[1056 + j];
  #pragma unroll
  for (int i = 0; i < DD; ++i) {
    float x = hid[i];
    #pragma unroll
    for (int j = 0; j < DD; ++j) hnew[j] = fmaf(x, sw[800 + i * DD + j], hnew[j]);
  }
  #pragma unroll
  for (int j = 0; j < DD; ++j) hnew[j] = fmaf(ALPHA, hnew[j], hv[j]);
  store16(h + (size_t)n * DD, hnew);

  uint4 pa, pb;
  pa.x = f2bf(hnew[0])  | (f2bf(hnew[1])  << 16);
  pa.y = f2bf(hnew[2])  | (f2bf(hnew[3])  << 16);
  pa.z = f2bf(hnew[4])  | (f2bf(hnew[5])  << 16);
  pa.w = f2bf(hnew[6])  | (f2bf(hnew[7])  << 16);
  pb.x = f2bf(hnew[8])  | (f2bf(hnew[9])  << 16);
  pb.y = f2bf(hnew[10]) | (f2bf(hnew[11]) << 16);
  pb.z = f2bf(hnew[12]) | (f2bf(hnew[13]) << 16);
  pb.w = f2bf(hnew[14]) | (f2bf(hnew[15]) << 16);
  *(uint4*)(hb + (size_t)n * DD)     = pa;
  *(uint4*)(hb + (size_t)n * DD + 8) = pb;

  float hid2[DD];
  #pragma unroll
  for (int j = 0; j < DD; ++j) hid2[j] = sw[1328 + j];
  #pragma unroll
  for (int i = 0; i < DD; ++i) {
    float x = hnew[i];
    #pragma unroll
    for (int j = 0; j < DD; ++j) hid2[j] = fmaf(x, sw[1072 + i * DD + j], hid2[j]);
  }
  float uo = sw[1360];
  #pragma unroll
  for (int i = 0; i < DD; ++i) uo += fmaxf(hid2[i], 0.0f) * sw[1344 + i];
  u[n] = uo;
}

extern "C" void kernel_launch(void* const* d_in, const int* in_sizes, int n_in,
                              void* d_out, int out_size, void* d_ws, size_t ws_size,
                              hipStream_t stream) {
  const int*   ei        = (const int*)d_in[0];
  const float* ea        = (const float*)d_in[1];
  const float* a_ij      = (const float*)d_in[2];
  const float* prb       = (const float*)d_in[3];
  const float* y         = (const float*)d_in[5];
  const float* phi_to_w1 = (const float*)d_in[6];
  const float* phi_to_b1 = (const float*)d_in[7];
  const float* phi_to_w2 = (const float*)d_in[8];
  const float* phi_to_b2 = (const float*)d_in[9];
  const float* phi_fr_w1 = (const float*)d_in[10];
  const float* phi_fr_b1 = (const float*)d_in[11];
  const float* phi_fr_w2 = (const float*)d_in[12];
  const float* phi_fr_b2 = (const float*)d_in[13];
  const float* psi_w1    = (const float*)d_in[14];
  const float* psi_b1    = (const float*)d_in[15];
  const float* psi_w2    = (const float*)d_in[16];
  const float* psi_b2    = (const float*)d_in[17];
  const float* dec_w1    = (const float*)d_in[18];
  const float* dec_b1    = (const float*)d_in[19];
  const float* dec_w2    = (const float*)d_in[20];
  const float* dec_b2    = (const float*)d_in[21];

  float* out_u    = (float*)d_out;
  float* out_loss = out_u + NN;

  char* wp = (char*)d_ws;
  auto carve = [&](size_t bytes) { void* p = (void*)wp; wp += (bytes + 15) & ~(size_t)15; return p; };
  uint4*  pay      = (uint4*)carve((size_t)2 * NE * 16);   // [dst-sorted | src-sorted]
  float2* pay_au   = (float2*)carve((size_t)NE * 8);
  float*  h        = (float*)carve((size_t)NN * DD * 4);
  unsigned short* hb16 = (unsigned short*)carve((size_t)NN * DD * 2);
  float*  mto      = (float*)carve((size_t)NN * DD * 4);
  float*  mfr      = (float*)carve((size_t)NN * DD * 4);
  unsigned short* rank_dst = (unsigned short*)carve((size_t)NE * 2);
  unsigned short* rank_src = (unsigned short*)carve((size_t)NE * 2);
  int*    base     = (int*)carve((size_t)(2 * NN + 1) * 4);
  int*    hist     = (int*)carve((size_t)2 * NN * 4);
  int*    sums     = (int*)carve(256 * 4);

  hipMemsetAsync(h, 0, (size_t)NN * DD * 4, stream);
  hipMemsetAsync(out_loss, 0, 4, stream);
  hipMemsetAsync(hist, 0, (size_t)2 * NN * 4, stream);

  const int EB  = (NE + 255) / 256;             // 3125
  const int NB  = (NN + 255) / 256;             // 391
  const int L2N = 2 * NN;                       // 200000
  const int SB1 = (L2N + 1023) / 1024;          // 196
  const int SB3 = (L2N + 255) / 256;            // 782
  const int GBK = 2 * NB0;                      // 782 gather blocks

  hist_kernel<<<EB, 256, 0, stream>>>(ei, hist, rank_dst, rank_src);
  scan1_kernel<<<SB1, 256, 0, stream>>>(hist, base, sums, L2N);
  scan2_kernel<<<1, 256, 0, stream>>>(sums, SB1, base + L2N);
  scan3_kernel<<<SB3, 256, 0, stream>>>(base, sums, L2N);
  scatter_kernel<<<EB, 256, 0, stream>>>(ei, ea, a_ij, base, rank_dst, rank_src,
                                         pay, pay_au);

  const float gw[3] = {0.81f, 0.9f, 1.0f};  // gamma^(K-1-t)

  // t = 0 (h == 0)
  gather_kernel<true, false><<<GBK, 256, 0, stream>>>(
      h, hb16, pay, base,
      phi_to_w1, phi_to_b1, phi_to_w2, phi_to_b2,
      phi_fr_w1, phi_fr_b1, phi_fr_w2, phi_fr_b2,
      mto, mfr, GBK, pay_au, out_u, y, 0.0f, out_loss);
  node_kernel<<<NB, 256, 0, stream>>>(
      h, hb16, mto, mfr, prb,
      psi_w1, psi_b1, psi_w2, psi_b2,
      dec_w1, dec_b1, dec_w2, dec_b2, out_u);

  // t = 1, 2: gather(t) fused with au_loss(t-1)
  for (int t = 1; t < 3; ++t) {
    gather_kernel<false, true><<<GBK + NB, 256, 0, stream>>>(
        h, hb16, pay, base,
        phi_to_w1 + t * 560, phi_to_b1 + t * 16, phi_to_w2 + t * 256, phi_to_b2 + t * 16,
        phi_fr_w1 + t * 560, phi_fr_b1 + t * 16, phi_fr_w2 + t * 256, phi_fr_b2 + t * 16,
        mto, mfr, GBK, pay_au, out_u, y, gw[t - 1] / (float)NN, out_loss);
    node_kernel<<<NB, 256, 0, stream>>>(
        h, hb16, mto, mfr, prb,
        psi_w1 + t * 784, psi_b1 + t * 16, psi_w2 + t * 256, psi_b2 + t * 16,
        dec_w1 + t * 256, dec_b1 + t * 16, dec_w2 + t * 16, dec_b2 + t, out_u);
  }

  // final residual loss (t = 2's u)
  gather_kernel<false, true><<<NB, 256, 0, stream>>>(
      h, hb16, pay, base,
      phi_to_w1, phi_to_b1, phi_to_w2, phi_to_b2,
      phi_fr_w1, phi_fr_b1, phi_fr_w2, phi_fr_b2,
      mto, mfr, 0, pay_au, out_u, y, gw[2] / (float)NN, out_loss);
}

// Round 7
// 342.999 us; speedup vs baseline: 2.8685x; 2.8685x over previous
//
#include <hip/hip_runtime.h>

#define NN 100000
#define NE 800000
#define DD 16
#define ALPHA 0.1f

__device__ __forceinline__ void load16(const float* __restrict__ p, float* r) {
  float4 v0 = *(const float4*)(p + 0);
  float4 v1 = *(const float4*)(p + 4);
  float4 v2 = *(const float4*)(p + 8);
  float4 v3 = *(const float4*)(p + 12);
  r[0]=v0.x; r[1]=v0.y; r[2]=v0.z; r[3]=v0.w;
  r[4]=v1.x; r[5]=v1.y; r[6]=v1.z; r[7]=v1.w;
  r[8]=v2.x; r[9]=v2.y; r[10]=v2.z; r[11]=v2.w;
  r[12]=v3.x; r[13]=v3.y; r[14]=v3.z; r[15]=v3.w;
}

__device__ __forceinline__ void store16(float* __restrict__ p, const float* r) {
  *(float4*)(p + 0)  = make_float4(r[0], r[1], r[2], r[3]);
  *(float4*)(p + 4)  = make_float4(r[4], r[5], r[6], r[7]);
  *(float4*)(p + 8)  = make_float4(r[8], r[9], r[10], r[11]);
  *(float4*)(p + 12) = make_float4(r[12], r[13], r[14], r[15]);
}

__device__ __forceinline__ unsigned f2bf(float x) {  // RNE f32 -> bf16 bits
  unsigned b = __float_as_uint(x);
  return (b + 0x7FFFu + ((b >> 16) & 1u)) >> 16;
}

// ---------------------------------------------------------------------------
// hist + rank over unified [in | out] histogram of length 2N
// ---------------------------------------------------------------------------
__global__ __launch_bounds__(256) void hist_kernel(
    const int* __restrict__ ei, int* __restrict__ hist,
    int* __restrict__ rank_dst, int* __restrict__ rank_src)
{
  int e = blockIdx.x * 256 + threadIdx.x;
  if (e >= NE) return;
  int s = ei[e];
  int d = ei[NE + e];
  rank_dst[e] = atomicAdd(&hist[d], 1);
  rank_src[e] = atomicAdd(&hist[NN + s], 1);
}

__global__ __launch_bounds__(256) void scan1_kernel(
    const int* __restrict__ in, int* __restrict__ out, int* __restrict__ sums, int L)
{
  __shared__ int sh[256];
  int t = threadIdx.x;
  int i0 = blockIdx.x * 1024 + t * 4;
  int v0 = (i0 + 0 < L) ? in[i0 + 0] : 0;
  int v1 = (i0 + 1 < L) ? in[i0 + 1] : 0;
  int v2 = (i0 + 2 < L) ? in[i0 + 2] : 0;
  int v3 = (i0 + 3 < L) ? in[i0 + 3] : 0;
  int tot = v0 + v1 + v2 + v3;
  sh[t] = tot;
  __syncthreads();
  int val = tot;
  for (int off = 1; off < 256; off <<= 1) {
    int x = (t >= off) ? sh[t - off] : 0;
    __syncthreads();
    val += x; sh[t] = val;
    __syncthreads();
  }
  if (t == 255) sums[blockIdx.x] = val;
  int run = val - tot;
  if (i0 + 0 < L) out[i0 + 0] = run; run += v0;
  if (i0 + 1 < L) out[i0 + 1] = run; run += v1;
  if (i0 + 2 < L) out[i0 + 2] = run; run += v2;
  if (i0 + 3 < L) out[i0 + 3] = run;
}

__global__ __launch_bounds__(256) void scan2_kernel(
    int* __restrict__ sums, int nb, int* __restrict__ out_total)
{
  __shared__ int sh[256];
  int t = threadIdx.x;
  int v = (t < nb) ? sums[t] : 0;
  sh[t] = v;
  __syncthreads();
  int val = v;
  for (int off = 1; off < 256; off <<= 1) {
    int x = (t >= off) ? sh[t - off] : 0;
    __syncthreads();
    val += x; sh[t] = val;
    __syncthreads();
  }
  if (t < nb) sums[t] = val - v;
  if (t == 255) *out_total = val;   // sentinel = 2*NE at base[2N]
}

__global__ __launch_bounds__(256) void scan3_kernel(
    int* __restrict__ out, const int* __restrict__ sums, int L)
{
  int i = blockIdx.x * 256 + threadIdx.x;
  if (i < L) out[i] += sums[i >> 10];
}

// atomic-free payload scatter into unified pay[2*NE]
__global__ __launch_bounds__(256) void scatter_kernel(
    const int* __restrict__ ei, const float* __restrict__ ea, const float* __restrict__ a,
    const int* __restrict__ base,
    const int* __restrict__ rank_dst, const int* __restrict__ rank_src,
    float4* __restrict__ pay, float2* __restrict__ pay_au)
{
  int e = blockIdx.x * 256 + threadIdx.x;
  if (e >= NE) return;
  int s = ei[e];
  int d = ei[NE + e];
  float e0 = ea[3 * (size_t)e], e1 = ea[3 * (size_t)e + 1], e2 = ea[3 * (size_t)e + 2];
  int sl = (s == d);
  int pd = base[d] + rank_dst[e];
  pay[pd] = make_float4(__int_as_float(sl ? -1 : s), e0, e1, e2);
  int ps = base[NN + s] + rank_src[e];
  pay[ps] = make_float4(__int_as_float(sl ? -1 : d), e0, e1, e2);
  pay_au[ps - NE] = make_float2(__int_as_float(d), a[e]);
}

// ---------------------------------------------------------------------------
// Degree-bucket permutation of the 2N (node,dir) groups (64 buckets).
// Hierarchical: LDS histogram per block -> one global atomic per (block,bin).
// ---------------------------------------------------------------------------
__global__ __launch_bounds__(256) void dbucket_kernel(
    const int* __restrict__ base, int* __restrict__ dhist)
{
  __shared__ int lh[64];
  int t = threadIdx.x;
  if (t < 64) lh[t] = 0;
  __syncthreads();
  int g = blockIdx.x * 256 + t;
  if (g < 2 * NN) {
    int dg = base[g + 1] - base[g];
    atomicAdd(&lh[min(dg, 63)], 1);
  }
  __syncthreads();
  if (t < 64 && lh[t]) atomicAdd(&dhist[t], lh[t]);
}

__global__ void dscan64_kernel(int* __restrict__ dhist)
{
  int t = threadIdx.x;   // 64 threads
  int v = dhist[t];
  int x = v;
  #pragma unroll
  for (int off = 1; off < 64; off <<= 1) {
    int y = __shfl_up(x, off, 64);
    if (t >= off) x += y;
  }
  dhist[t] = x - v;      // exclusive base; becomes cursor for dperm
}

__global__ __launch_bounds__(256) void dperm_kernel(
    const int* __restrict__ base, int* __restrict__ dhist, int* __restrict__ perm)
{
  __shared__ int lh[64];
  __shared__ int lb[64];
  int t = threadIdx.x;
  if (t < 64) lh[t] = 0;
  __syncthreads();
  int g = blockIdx.x * 256 + t;
  int b = 0, r = 0;
  bool v = (g < 2 * NN);
  if (v) {
    int dg = base[g + 1] - base[g];
    b = min(dg, 63);
    r = atomicAdd(&lh[b], 1);
  }
  __syncthreads();
  if (t < 64 && lh[t]) lb[t] = atomicAdd(&dhist[t], lh[t]);
  __syncthreads();
  if (v) perm[lb[b] + r] = g;
}

// ---------------------------------------------------------------------------
// Gather: 8-lane subgroup per degree-sorted (node,dir) group. Cooperative p1
// (each lane computes 2 of 16 outputs, exchange via LDS). Lanes stride the
// group's edge list, accumulate sum(relu(hid)), shfl_xor-reduce, layer 2
// feature-split (2 outputs/lane). au blocks: residual loss for prev u.
// ---------------------------------------------------------------------------
template<bool FIRST, bool WITH_AU>
__global__ __launch_bounds__(256) void gather_kernel(
    const float* __restrict__ h, const unsigned short* __restrict__ hb,
    const float4* __restrict__ pay, const int* __restrict__ base,
    const int* __restrict__ perm,
    const float* __restrict__ to_w1, const float* __restrict__ to_b1,
    const float* __restrict__ to_w2, const float* __restrict__ to_b2,
    const float* __restrict__ fr_w1, const float* __restrict__ fr_b1,
    const float* __restrict__ fr_w2, const float* __restrict__ fr_b2,
    float* __restrict__ mto, float* __restrict__ mfr, int gblocks,
    const float2* __restrict__ pay_au, const float* __restrict__ u,
    const float* __restrict__ y, float w, float* __restrict__ loss)
{
  if (WITH_AU && (int)blockIdx.x >= gblocks) {
    // ---- au_loss body ----
    __shared__ float ss[4];
    int n = (blockIdx.x - gblocks) * 256 + threadIdx.x;
    float acc = 0.0f;
    if (n < NN) {
      float au = 0.0f;
      int beg = base[NN + n] - NE, end = base[NN + n + 1] - NE;
      for (int i = beg; i < end; ++i) {
        float2 q = pay_au[i];
        au = fmaf(q.y, u[__float_as_int(q.x)], au);
      }
      float dlt = au - y[n];
      acc = dlt * dlt;
    }
    #pragma unroll
    for (int off = 32; off > 0; off >>= 1) acc += __shfl_down(acc, off);
    int lane = threadIdx.x & 63, wid = threadIdx.x >> 6;
    if (lane == 0) ss[wid] = acc;
    __syncthreads();
    if (threadIdx.x == 0) atomicAdd(loss, (ss[0] + ss[1] + ss[2] + ss[3]) * w);
    return;
  }

  // ---- gather body (grid sized so every thread maps to a valid subgroup) ----
  __shared__ float sw[1696];     // per half (848): w1[560] b1@560 w2@576 b2@832
  __shared__ float p1buf[512];   // cooperative p1 exchange (2 floats/thread)
  int t = threadIdx.x;
  for (int i = t; i < 560; i += 256) { sw[i] = to_w1[i]; sw[848 + i] = fr_w1[i]; }
  { int i = t;
    if (i < 256) { sw[576 + i] = to_w2[i]; sw[848 + 576 + i] = fr_w2[i]; }
    if (i < 16) {
      sw[560 + i] = to_b1[i];
      sw[832 + i] = to_b2[i];
      sw[848 + 560 + i] = fr_b1[i];
      sw[848 + 832 + i] = fr_b2[i];
    }
  }
  __syncthreads();

  int sub = (blockIdx.x * 256 + t) >> 3;   // subgroup index (exact: 2N*8 threads)
  int l = t & 7;
  int g = perm[sub];                       // degree-sorted group
  int dir = (g >= NN) ? 1 : 0;             // 0 = mess_to (dst half), 1 = mess_from
  int n = g - (dir ? NN : 0);

  const float* w1 = sw + (dir ? 848 : 0);
  const float* b1 = w1 + 560;
  const float* w2 = w1 + 576;
  const float* b2 = w1 + 832;

  float p1v[DD];
  if (FIRST) {
    #pragma unroll
    for (int j = 0; j < DD; ++j) p1v[j] = b1[j];
  } else {
    // cooperative p1: lane l computes outputs 2l, 2l+1 (32 FMA), exchange via LDS
    float hv[DD];
    load16(h + (size_t)n * DD, hv);
    int j0 = 2 * l;
    float pa = b1[j0], pb = b1[j0 + 1];
    #pragma unroll
    for (int k = 0; k < DD; ++k) {
      pa = fmaf(hv[k], w1[k * DD + j0], pa);
      pb = fmaf(hv[k], w1[k * DD + j0 + 1], pb);
    }
    p1buf[2 * t] = pa;
    p1buf[2 * t + 1] = pb;
    __syncthreads();
    const float* pbase = &p1buf[(t & ~7) * 2];
    #pragma unroll
    for (int j = 0; j < DD; ++j) p1v[j] = pbase[j];
  }

  float hs_[DD];
  #pragma unroll
  for (int j = 0; j < DD; ++j) hs_[j] = 0.0f;
  int cnt = 0;

  int beg = base[g], end = base[g + 1];
  for (int i = beg + l; i < end; i += 8) {
    float4 q = pay[i];
    int nb = __float_as_int(q.x);
    if (nb >= 0) {
      float hid[DD];
      #pragma unroll
      for (int j = 0; j < DD; ++j)
        hid[j] = fmaf(q.y, w1[32 * DD + j],
                 fmaf(q.z, w1[33 * DD + j],
                 fmaf(q.w, w1[34 * DD + j], p1v[j])));
      if (!FIRST) {
        uint4 qa = *(const uint4*)(hb + (size_t)nb * DD);
        uint4 qb = *(const uint4*)(hb + (size_t)nb * DD + 8);
        float hv[DD];
        hv[0]  = __uint_as_float(qa.x << 16); hv[1]  = __uint_as_float(qa.x & 0xFFFF0000u);
        hv[2]  = __uint_as_float(qa.y << 16); hv[3]  = __uint_as_float(qa.y & 0xFFFF0000u);
        hv[4]  = __uint_as_float(qa.z << 16); hv[5]  = __uint_as_float(qa.z & 0xFFFF0000u);
        hv[6]  = __uint_as_float(qa.w << 16); hv[7]  = __uint_as_float(qa.w & 0xFFFF0000u);
        hv[8]  = __uint_as_float(qb.x << 16); hv[9]  = __uint_as_float(qb.x & 0xFFFF0000u);
        hv[10] = __uint_as_float(qb.y << 16); hv[11] = __uint_as_float(qb.y & 0xFFFF0000u);
        hv[12] = __uint_as_float(qb.z << 16); hv[13] = __uint_as_float(qb.z & 0xFFFF0000u);
        hv[14] = __uint_as_float(qb.w << 16); hv[15] = __uint_as_float(qb.w & 0xFFFF0000u);
        #pragma unroll
        for (int k = 0; k < DD; ++k) {
          float x = hv[k];
          #pragma unroll
          for (int j = 0; j < DD; ++j) hid[j] = fmaf(x, w1[(DD + k) * DD + j], hid[j]);
        }
      }
      #pragma unroll
      for (int j = 0; j < DD; ++j) hs_[j] += fmaxf(hid[j], 0.0f);
      ++cnt;
    }
  }

  // reduce across the 8-lane subgroup
  #pragma unroll
  for (int j = 0; j < DD; ++j) {
    hs_[j] += __shfl_xor(hs_[j], 1, 64);
    hs_[j] += __shfl_xor(hs_[j], 2, 64);
    hs_[j] += __shfl_xor(hs_[j], 4, 64);
  }
  cnt += __shfl_xor(cnt, 1, 64);
  cnt += __shfl_xor(cnt, 2, 64);
  cnt += __shfl_xor(cnt, 4, 64);

  // layer 2 once per group, feature-split: lane l emits outputs [2l, 2l+2)
  float c = (float)cnt;
  float m0 = c * b2[2 * l + 0];
  float m1 = c * b2[2 * l + 1];
  #pragma unroll
  for (int k = 0; k < DD; ++k) {
    float x = hs_[k];
    m0 = fmaf(x, w2[k * DD + 2 * l + 0], m0);
    m1 = fmaf(x, w2[k * DD + 2 * l + 1], m1);
  }
  float* dst = (dir ? mfr : mto) + (size_t)n * DD + 2 * l;
  *(float2*)dst = make_float2(m0, m1);
}

// ---------------------------------------------------------------------------
// Node kernel: h += ALPHA * psi([h, mto, mfr, prb]); u = dec(h); hb = bf16(h)
// ---------------------------------------------------------------------------
__global__ __launch_bounds__(256) void node_kernel(
    float* __restrict__ h, unsigned short* __restrict__ hb,
    const float* __restrict__ mto, const float* __restrict__ mfr,
    const float* __restrict__ prb,
    const float* __restrict__ psi_w1, const float* __restrict__ psi_b1,
    const float* __restrict__ psi_w2, const float* __restrict__ psi_b2,
    const float* __restrict__ dec_w1, const float* __restrict__ dec_b1,
    const float* __restrict__ dec_w2, const float* __restrict__ dec_b2,
    float* __restrict__ u)
{
  __shared__ float sw[1361];
  for (int i = threadIdx.x; i < 784; i += 256) sw[i] = psi_w1[i];
  { int i = threadIdx.x;
    if (i < 256) { sw[800 + i] = psi_w2[i]; sw[1072 + i] = dec_w1[i]; }
    if (i < 16) {
      sw[784 + i] = psi_b1[i];
      sw[1056 + i] = psi_b2[i];
      sw[1328 + i] = dec_b1[i];
      sw[1344 + i] = dec_w2[i];
    }
    if (i == 0) sw[1360] = dec_b2[0];
  }
  __syncthreads();

  int n = blockIdx.x * 256 + threadIdx.x;
  if (n >= NN) return;

  float hv[DD], mt[DD], mf[DD];
  load16(h + (size_t)n * DD, hv);
  load16(mto + (size_t)n * DD, mt);
  load16(mfr + (size_t)n * DD, mf);
  float p = prb[n];

  float hid[DD];
  #pragma unroll
  for (int j = 0; j < DD; ++j) hid[j] = sw[784 + j];
  #pragma unroll
  for (int i = 0; i < DD; ++i) {
    float x = hv[i];
    #pragma unroll
    for (int j = 0; j < DD; ++j) hid[j] = fmaf(x, sw[i * DD + j], hid[j]);
  }
  #pragma unroll
  for (int i = 0; i < DD; ++i) {
    float x = mt[i];
    #pragma unroll
    for (int j = 0; j < DD; ++j) hid[j] = fmaf(x, sw[(DD + i) * DD + j], hid[j]);
  }
  #pragma unroll
  for (int i = 0; i < DD; ++i) {
    float x = mf[i];
    #pragma unroll
    for (int j = 0; j < DD; ++j) hid[j] = fmaf(x, sw[(2 * DD + i) * DD + j], hid[j]);
  }
  #pragma unroll
  for (int j = 0; j < DD; ++j) hid[j] = fmaf(p, sw[48 * DD + j], hid[j]);
  #pragma unroll
  for (int j = 0; j < DD; ++j) hid[j] = fmaxf(hid[j], 0.0f);

  float hnew[DD];
  #pragma unroll
  for (int j = 0; j < DD; ++j) hnew[j] = sw[1056 + j];
  #pragma unroll
  for (int i = 0; i < DD; ++i) {
    float x = hid[i];
    #pragma unroll
    for (int j = 0; j < DD; ++j) hnew[j] = fmaf(x, sw[800 + i * DD + j], hnew[j]);
  }
  #pragma unroll
  for (int j = 0; j < DD; ++j) hnew[j] = fmaf(ALPHA, hnew[j], hv[j]);
  store16(h + (size_t)n * DD, hnew);

  uint4 pa, pb;
  pa.x = f2bf(hnew[0])  | (f2bf(hnew[1])  << 16);
  pa.y = f2bf(hnew[2])  | (f2bf(hnew[3])  << 16);
  pa.z = f2bf(hnew[4])  | (f2bf(hnew[5])  << 16);
  pa.w = f2bf(hnew[6])  | (f2bf(hnew[7])  << 16);
  pb.x = f2bf(hnew[8])  | (f2bf(hnew[9])  << 16);
  pb.y = f2bf(hnew[10]) | (f2bf(hnew[11]) << 16);
  pb.z = f2bf(hnew[12]) | (f2bf(hnew[13]) << 16);
  pb.w = f2bf(hnew[14]) | (f2bf(hnew[15]) << 16);
  *(uint4*)(hb + (size_t)n * DD)     = pa;
  *(uint4*)(hb + (size_t)n * DD + 8) = pb;

  float hid2[DD];
  #pragma unroll
  for (int j = 0; j < DD; ++j) hid2[j] = sw[1328 + j];
  #pragma unroll
  for (int i = 0; i < DD; ++i) {
    float x = hnew[i];
    #pragma unroll
    for (int j = 0; j < DD; ++j) hid2[j] = fmaf(x, sw[1072 + i * DD + j], hid2[j]);
  }
  float uo = sw[1360];
  #pragma unroll
  for (int i = 0; i < DD; ++i) uo += fmaxf(hid2[i], 0.0f) * sw[1344 + i];
  u[n] = uo;
}

extern "C" void kernel_launch(void* const* d_in, const int* in_sizes, int n_in,
                              void* d_out, int out_size, void* d_ws, size_t ws_size,
                              hipStream_t stream) {
  const int*   ei        = (const int*)d_in[0];
  const float* ea        = (const float*)d_in[1];
  const float* a_ij      = (const float*)d_in[2];
  const float* prb       = (const float*)d_in[3];
  const float* y         = (const float*)d_in[5];
  const float* phi_to_w1 = (const float*)d_in[6];
  const float* phi_to_b1 = (const float*)d_in[7];
  const float* phi_to_w2 = (const float*)d_in[8];
  const float* phi_to_b2 = (const float*)d_in[9];
  const float* phi_fr_w1 = (const float*)d_in[10];
  const float* phi_fr_b1 = (const float*)d_in[11];
  const float* phi_fr_w2 = (const float*)d_in[12];
  const float* phi_fr_b2 = (const float*)d_in[13];
  const float* psi_w1    = (const float*)d_in[14];
  const float* psi_b1    = (const float*)d_in[15];
  const float* psi_w2    = (const float*)d_in[16];
  const float* psi_b2    = (const float*)d_in[17];
  const float* dec_w1    = (const float*)d_in[18];
  const float* dec_b1    = (const float*)d_in[19];
  const float* dec_w2    = (const float*)d_in[20];
  const float* dec_b2    = (const float*)d_in[21];

  float* out_u    = (float*)d_out;
  float* out_loss = out_u + NN;

  char* wp = (char*)d_ws;
  auto carve = [&](size_t bytes) { void* p = (void*)wp; wp += (bytes + 15) & ~(size_t)15; return p; };
  float4* pay      = (float4*)carve((size_t)2 * NE * 16);   // [dst-sorted | src-sorted]
  float2* pay_au   = (float2*)carve((size_t)NE * 8);
  float*  h        = (float*)carve((size_t)NN * DD * 4);
  unsigned short* hb16 = (unsigned short*)carve((size_t)NN * DD * 2);
  float*  mto      = (float*)carve((size_t)NN * DD * 4);
  float*  mfr      = (float*)carve((size_t)NN * DD * 4);
  int*    rank_dst = (int*)carve((size_t)NE * 4);
  int*    rank_src = (int*)carve((size_t)NE * 4);
  int*    base     = (int*)carve((size_t)(2 * NN + 1) * 4);
  int*    hist     = (int*)carve((size_t)2 * NN * 4);
  int*    sums     = (int*)carve(256 * 4);
  int*    dhist    = (int*)carve(64 * 4);
  int*    perm     = rank_dst;   // alias: rank_dst dead after scatter

  hipMemsetAsync(h, 0, (size_t)NN * DD * 4, stream);
  hipMemsetAsync(out_loss, 0, 4, stream);
  hipMemsetAsync(hist, 0, (size_t)2 * NN * 4, stream);
  hipMemsetAsync(dhist, 0, 64 * 4, stream);

  const int EB  = (NE + 255) / 256;             // 3125
  const int NB  = (NN + 255) / 256;             // 391
  const int L2N = 2 * NN;                       // 200000
  const int SB1 = (L2N + 1023) / 1024;          // 196
  const int SB3 = (L2N + 255) / 256;            // 782
  const int DB  = (L2N + 255) / 256;            // 782
  const int GB8 = (L2N * 8) / 256;              // 6250 (exact)

  hist_kernel<<<EB, 256, 0, stream>>>(ei, hist, rank_dst, rank_src);
  scan1_kernel<<<SB1, 256, 0, stream>>>(hist, base, sums, L2N);
  scan2_kernel<<<1, 256, 0, stream>>>(sums, SB1, base + L2N);
  scan3_kernel<<<SB3, 256, 0, stream>>>(base, sums, L2N);
  scatter_kernel<<<EB, 256, 0, stream>>>(ei, ea, a_ij, base, rank_dst, rank_src,
                                         pay, pay_au);
  // degree-bucket permutation (after scatter: perm aliases rank_dst)
  dbucket_kernel<<<DB, 256, 0, stream>>>(base, dhist);
  dscan64_kernel<<<1, 64, 0, stream>>>(dhist);
  dperm_kernel<<<DB, 256, 0, stream>>>(base, dhist, perm);

  const float gw[3] = {0.81f, 0.9f, 1.0f};  // gamma^(K-1-t)

  // t = 0 (h == 0)
  gather_kernel<true, false><<<GB8, 256, 0, stream>>>(
      h, hb16, pay, base, perm,
      phi_to_w1, phi_to_b1, phi_to_w2, phi_to_b2,
      phi_fr_w1, phi_fr_b1, phi_fr_w2, phi_fr_b2,
      mto, mfr, GB8, pay_au, out_u, y, 0.0f, out_loss);
  node_kernel<<<NB, 256, 0, stream>>>(
      h, hb16, mto, mfr, prb,
      psi_w1, psi_b1, psi_w2, psi_b2,
      dec_w1, dec_b1, dec_w2, dec_b2, out_u);

  // t = 1, 2: gather(t) fused with au_loss(t-1)
  for (int t = 1; t < 3; ++t) {
    gather_kernel<false, true><<<GB8 + NB, 256, 0, stream>>>(
        h, hb16, pay, base, perm,
        phi_to_w1 + t * 560, phi_to_b1 + t * 16, phi_to_w2 + t * 256, phi_to_b2 + t * 16,
        phi_fr_w1 + t * 560, phi_fr_b1 + t * 16, phi_fr_w2 + t * 256, phi_fr_b2 + t * 16,
        mto, mfr, GB8, pay_au, out_u, y, gw[t - 1] / (float)NN, out_loss);
    node_kernel<<<NB, 256, 0, stream>>>(
        h, hb16, mto, mfr, prb,
        psi_w1 + t * 784, psi_b1 + t * 16, psi_w2 + t * 256, psi_b2 + t * 16,
        dec_w1 + t * 256, dec_b1 + t * 16, dec_w2 + t * 16, dec_b2 + t, out_u);
  }

  // final residual loss (t = 2's u)
  gather_kernel<false, true><<<NB, 256, 0, stream>>>(
      h, hb16, pay, base, perm,
      phi_to_w1, phi_to_b1, phi_to_w2, phi_to_b2,
      phi_fr_w1, phi_fr_b1, phi_fr_w2, phi_fr_b2,
      mto, mfr, 0, pay_au, out_u, y, gw[2] / (float)NN, out_loss);
}